// Round 5
// baseline (124.562 us; speedup 1.0000x reference)
//
#include <hip/hip_runtime.h>
#include <stdint.h>

#define N_ 256
#define H_ 1024
#define BS_ 128

// ---------------- workspace layout (floats), all plain stores ----------------
// sk   : [128][1024]        @ 0          1 - tk^2
// oacc : [3][128][256]      @ 131072     reduced fo/go/ko
// opart: [32][3][128][256]  @ 229376     layer2 k-split partials (32 slices)
// jpart: [16][2][128][256]  @ 3375104    J h-split partials
#define WS_SK    0
#define WS_OACC  131072
#define WS_OPART 229376
#define WS_JPART 3375104
#define WS_FLOATS 4423680   // ~17.7 MB (harness ws is ~256 MB)

__device__ __forceinline__ float dot4(float4 a, float4 b) {
    return a.x * b.x + a.y * b.y + a.z * b.z + a.w * b.w;
}

// ---- K12T: fused layer1+layer2 with 4x4 register tiles, bank-optimal LDS ----
// grid = 768 = 96 groups (m, ht 32-h slice) x 8 row-tiles (16 rows); 256 thr.
// LDS ~50.5 KB -> 3 blocks/CU (12 waves). Reads/fma4 = 0.5 (was ~1.1):
//   phase1: thread = (hl 4h-slot, ke 32k-slice, rq 4r-slot); 4h x 4r tile,
//           k-chunk kappa = c*8+ke puts ke in low bank bits (8-way optimal);
//           shuffle-xor over lane bits 3..5 reduces the 8-way k-split.
//   phase2: thread = (is 4i-slot, rq 4r-slot); 4i x 4r tile, full 32-h k;
//           ts reads are pure wave-broadcast; float4 coalesced C-stores.
__global__ __launch_bounds__(256) void k12t(
    const float* __restrict__ x,
    const float* __restrict__ Wf1, const float* __restrict__ bf1,
    const float* __restrict__ Wg1, const float* __restrict__ bg1,
    const float* __restrict__ Wk1, const float* __restrict__ bk1,
    const float* __restrict__ Wf2, const float* __restrict__ bf2,
    const float* __restrict__ Wg2, const float* __restrict__ bg2,
    const float* __restrict__ Wk2, const float* __restrict__ bk2,
    float* __restrict__ sk, float* __restrict__ opart)
{
    const int bx  = blockIdx.x;
    const int sid = (bx & 7) * 96 + (bx >> 3);   // bijective XCD swizzle
    const int g   = sid >> 3;          // 0..95 weight group (m, ht)
    const int rt  = sid & 7;           // 0..7 row tile (16 rows)
    const int m   = g >> 5;            // 0..2
    const int ht  = g & 31;            // 0..31 h-slice of 32
    const int t   = threadIdx.x;
    const int h0  = ht * 32;
    const int r0  = rt * 16;

    const float* W1 = (m == 0) ? Wf1 : (m == 1) ? Wg1 : Wk1;
    const float* b1 = (m == 0) ? bf1 : (m == 1) ? bg1 : bk1;
    const float* W2 = (m == 0) ? Wf2 : (m == 1) ? Wg2 : Wk2;
    const float* b2 = (m == 0) ? bf2 : (m == 1) ? bg2 : bk2;

    __shared__ float4 wbuf[2048];                   // 32 KB: W1 then W2
    __shared__ __align__(16) float xs[16][260];     // 16.25 KB (pad: bank spread)
    __shared__ __align__(16) float ts[16][36];      //  2.25 KB (pad: broadcast rows)

    // ---- stage x (16 rows x 1KB) and W1 (32 rows x 1KB), both coalesced ----
    {
        const float4* xsrc = (const float4*)(x + r0 * N_);
        #pragma unroll
        for (int v = 0; v < 4; ++v) {
            const int u = t + 256 * v;              // 0..1023
            const int row = u >> 6, i = u & 63;
            ((float4*)(xs[row]))[i] = xsrc[u];      // row base 1040B, 16B-aligned
        }
        const float4* wg = (const float4*)(W1 + h0 * N_);
        #pragma unroll
        for (int v = 0; v < 8; ++v) {
            const int u = t + 256 * v;              // 0..2047
            const int row = u >> 6, c = u & 63;
            wbuf[(row << 6) | (c ^ (row & 7))] = wg[u];   // XOR by row&7
        }
    }
    __syncthreads();

    // ---- phase 1: 4h x 4r x 32k per thread ----
    {
        const int hl = t & 7;            // 4h-slot: h = h0 + hl*4 + hh
        const int ke = (t >> 3) & 7;     // 32k-slice (lane bits 3..5)
        const int rq = t >> 6;           // 4r-slot (wave-uniform)
        const int x4b = (hl & 1) << 2;   // (row&7) = x4b | hh for row = hl*4+hh

        float acc[4][4];                 // [hh][rr]
        #pragma unroll
        for (int a = 0; a < 4; ++a)
            #pragma unroll
            for (int b = 0; b < 4; ++b) acc[a][b] = 0.f;

        const float4* wbase = wbuf + ((hl * 4) << 6);
        #pragma unroll
        for (int c = 0; c < 8; ++c) {
            const int kap = c * 8 + ke;  // k-chunk; low3 = ke -> 8-way optimal
            const float4 w0 = wbase[0 * 64 + (kap ^ x4b ^ 0)];
            const float4 w1 = wbase[1 * 64 + (kap ^ x4b ^ 1)];
            const float4 w2v = wbase[2 * 64 + (kap ^ x4b ^ 2)];
            const float4 w3 = wbase[3 * 64 + (kap ^ x4b ^ 3)];
            #pragma unroll
            for (int rr = 0; rr < 4; ++rr) {
                const float4 xv =
                    *(const float4*)(xs[rq * 4 + rr] + kap * 4);
                acc[0][rr] += dot4(w0, xv);
                acc[1][rr] += dot4(w1, xv);
                acc[2][rr] += dot4(w2v, xv);
                acc[3][rr] += dot4(w3, xv);
            }
        }
        // butterfly-reduce the 8-way k-split (lane bits 3,4,5)
        #pragma unroll
        for (int a = 0; a < 4; ++a)
            #pragma unroll
            for (int b = 0; b < 4; ++b) {
                acc[a][b] += __shfl_xor(acc[a][b], 8, 64);
                acc[a][b] += __shfl_xor(acc[a][b], 16, 64);
                acc[a][b] += __shfl_xor(acc[a][b], 32, 64);
            }
        // ke-lane finalizes flat outputs {2ke, 2ke+1}: hh = ke>>1, rr = (ke&1)*2+j
        const int hh = ke >> 1;
        const int rb = (ke & 1) * 2;
        float o0 = acc[0][rb],     o1 = acc[0][rb + 1];
        o0 = (hh == 1) ? acc[1][rb] : o0;  o1 = (hh == 1) ? acc[1][rb + 1] : o1;
        o0 = (hh == 2) ? acc[2][rb] : o0;  o1 = (hh == 2) ? acc[2][rb + 1] : o1;
        o0 = (hh == 3) ? acc[3][rb] : o0;  o1 = (hh == 3) ? acc[3][rb + 1] : o1;
        const int hloc = hl * 4 + hh;
        const int h    = h0 + hloc;
        const float bv = b1[h];
        const float v0 = tanhf(o0 + bv), v1 = tanhf(o1 + bv);
        const int rl = rq * 4 + rb;
        ts[rl][hloc]     = v0;
        ts[rl + 1][hloc] = v1;
        if (m == 2) {
            sk[(r0 + rl) * H_ + h]     = 1.0f - v0 * v0;
            sk[(r0 + rl + 1) * H_ + h] = 1.0f - v1 * v1;
        }
    }
    __syncthreads();

    // ---- re-stage wbuf with W2 slice [256 i][8 f4-chunks of 32 h] ----
    {
        #pragma unroll
        for (int v = 0; v < 8; ++v) {
            const int u = t + 256 * v;              // 0..2047
            const int row = u >> 3, c = u & 7;      // 8 thr/row, 128B segments
            wbuf[(row << 3) | (c ^ ((row >> 2) & 7))] =
                ((const float4*)(W2 + row * H_ + h0))[c];
        }
    }
    __syncthreads();

    // ---- phase 2: 4i x 4r x 32h per thread; float4 coalesced stores ----
    {
        const int is = t & 63;           // 4i-slot: i = is*4 + ii
        const int rq = t >> 6;           // 4r-slot (wave-uniform)
        const int sw = is & 7;           // row-XOR (same for all 4 ii)

        float4 acc[4];                   // [rr], components = ii
        #pragma unroll
        for (int rr = 0; rr < 4; ++rr) acc[rr] = make_float4(0.f, 0.f, 0.f, 0.f);

        const float4* w2b = wbuf + ((is * 4) << 3);
        #pragma unroll
        for (int c = 0; c < 8; ++c) {
            const float4 wv0 = w2b[0 * 8 + (c ^ sw)];
            const float4 wv1 = w2b[1 * 8 + (c ^ sw)];
            const float4 wv2 = w2b[2 * 8 + (c ^ sw)];
            const float4 wv3 = w2b[3 * 8 + (c ^ sw)];
            #pragma unroll
            for (int rr = 0; rr < 4; ++rr) {
                const float4 av = *(const float4*)(ts[rq * 4 + rr] + c * 4);
                acc[rr].x += dot4(wv0, av);     // av is pure wave-broadcast
                acc[rr].y += dot4(wv1, av);
                acc[rr].z += dot4(wv2, av);
                acc[rr].w += dot4(wv3, av);
            }
        }
        if (ht == 0) {
            const int i = is * 4;
            const float4 bv = make_float4(b2[i], b2[i + 1], b2[i + 2], b2[i + 3]);
            #pragma unroll
            for (int rr = 0; rr < 4; ++rr) {
                acc[rr].x += bv.x; acc[rr].y += bv.y;
                acc[rr].z += bv.z; acc[rr].w += bv.w;
            }
        }
        #pragma unroll
        for (int rr = 0; rr < 4; ++rr) {
            const int r = r0 + rq * 4 + rr;
            ((float4*)(opart + ((ht * 3 + m) * BS_ + r) * N_))[is] = acc[rr];
        }
    }
}

// ---- K25: reduce opart (32 slices) -> oacc. grid = 384 ----
__global__ __launch_bounds__(256) void k25_reduce(
    const float* __restrict__ opart, float* __restrict__ oacc)
{
    const int tid = blockIdx.x * 256 + threadIdx.x;   // 0..98303
    float s = 0.f;
    #pragma unroll
    for (int ks = 0; ks < 32; ++ks)
        s += opart[ks * (3 * BS_ * N_) + tid];
    oacc[tid] = s;
}

// ---- K3: fused v+J partials, reads reduced oacc. grid = 512 (proven) ----
__global__ __launch_bounds__(256) void k3_vj(
    const float* __restrict__ Wk1, const float* __restrict__ Wk2,
    const float* __restrict__ oacc, const float* __restrict__ sk,
    float* __restrict__ jpart)
{
    const int q  = blockIdx.x & 15;    // 0..15 h-slice
    const int rp = blockIdx.x >> 4;    // 0..31 row tile
    const int t  = threadIdx.x;
    const int r0 = rp * 4;
    const int h0 = q * 64;

    __shared__ float fos[4][256], gos[4][256];   // 8 KB
    __shared__ float sfv[4][64], sgv[4][64];     // 2 KB

    for (int u = t; u < 1024; u += 256) {
        const int r = u >> 8, i = u & 255;
        fos[r][i] = oacc[(r0 + r) * N_ + i];
        gos[r][i] = oacc[(BS_ + r0 + r) * N_ + i];
    }
    __syncthreads();

    {
        const int hl = t & 63;
        const int rl = t >> 6;         // 0..3, wave-uniform
        const int h  = h0 + hl;
        const float* w2 = Wk2 + h;
        float vf = 0.f, vg = 0.f;
        #pragma unroll 8
        for (int c = 0; c < 64; ++c) {
            const float4 of = ((const float4*)fos[rl])[c];
            const float4 og = ((const float4*)gos[rl])[c];
            const float w0  = w2[(4 * c + 0) * H_];
            const float w1v = w2[(4 * c + 1) * H_];
            const float w2v = w2[(4 * c + 2) * H_];
            const float w3  = w2[(4 * c + 3) * H_];
            vf += of.x * w0 + of.y * w1v + of.z * w2v + of.w * w3;
            vg += og.x * w0 + og.y * w1v + og.z * w2v + og.w * w3;
        }
        const float s = sk[(r0 + rl) * H_ + h];
        sfv[rl][hl] = s * vf;
        sgv[rl][hl] = s * vg;
    }
    __syncthreads();

    {
        float jf[4] = {0.f, 0.f, 0.f, 0.f};
        float jg[4] = {0.f, 0.f, 0.f, 0.f};
        const float* w1 = Wk1 + h0 * N_ + t;    // coalesced over t
        #pragma unroll 4
        for (int c = 0; c < 16; ++c) {
            const float w0  = w1[(4 * c + 0) * N_];
            const float wv1 = w1[(4 * c + 1) * N_];
            const float wv2 = w1[(4 * c + 2) * N_];
            const float wv3 = w1[(4 * c + 3) * N_];
            #pragma unroll
            for (int r = 0; r < 4; ++r) {
                const float4 sf = ((const float4*)sfv[r])[c];
                const float4 sg = ((const float4*)sgv[r])[c];
                jf[r] += sf.x * w0 + sf.y * wv1 + sf.z * wv2 + sf.w * wv3;
                jg[r] += sg.x * w0 + sg.y * wv1 + sg.z * wv2 + sg.w * wv3;
            }
        }
        #pragma unroll
        for (int r = 0; r < 4; ++r) {
            jpart[((q * 2 + 0) * BS_ + r0 + r) * N_ + t] = jf[r];
            jpart[((q * 2 + 1) * BS_ + r0 + r) * N_ + t] = jg[r];
        }
    }
}

// ---- K4: reduce jpart + norms + mask + output. grid = 128 (proven) ----
__global__ __launch_bounds__(256) void k4_final(
    const float* __restrict__ oacc,
    const float* __restrict__ jpart,
    float* __restrict__ out)
{
    const int r = blockIdx.x;
    const int t = threadIdx.x;
    __shared__ float red[12];

    const float fo = oacc[r * N_ + t];
    const float go = oacc[(BS_ + r) * N_ + t];
    const float ko = oacc[(2 * BS_ + r) * N_ + t];

    float jf = 0.f, jg = 0.f;
    #pragma unroll
    for (int q = 0; q < 16; ++q) {
        jf += jpart[((q * 2 + 0) * BS_ + r) * N_ + t];
        jg += jpart[((q * 2 + 1) * BS_ + r) * N_ + t];
    }

    float v0 = ko * ko, v1 = jf * jf, v2 = ko * jg;
    #pragma unroll
    for (int o = 32; o > 0; o >>= 1) {
        v0 += __shfl_xor(v0, o, 64);
        v1 += __shfl_xor(v1, o, 64);
        v2 += __shfl_xor(v2, o, 64);
    }
    const int wid = t >> 6;
    if ((t & 63) == 0) {
        red[wid * 3 + 0] = v0;
        red[wid * 3 + 1] = v1;
        red[wid * 3 + 2] = v2;
    }
    __syncthreads();
    const float kn2 = red[0] + red[3] + red[6] + red[9];
    const float jf2 = red[1] + red[4] + red[7] + red[10];
    const float kjg = red[2] + red[5] + red[8] + red[11];

    const float knorm = sqrtf(kn2);
    const float kn4 = kn2 * kn2;
    const float kn8 = kn4 * kn4;
    const float c1 = sqrtf(jf2) - 60.0f * kn8 * knorm;
    const float c2 = kjg - 20.0f * kn8 * kn2;
    const float scale = ((c1 > 1e-8f) || (c2 < -1e-8f)) ? 0.5f : 1.0f;

    out[r * N_ + t] = (fo + go) * scale;
}

// ================= fallback: round-2 proven fused kernel =================
__global__ __launch_bounds__(256) void manifold_fused(
    const float* __restrict__ x,
    const float* __restrict__ Wf1, const float* __restrict__ bf1v,
    const float* __restrict__ Wf2, const float* __restrict__ bf2v,
    const float* __restrict__ Wg1, const float* __restrict__ bg1v,
    const float* __restrict__ Wg2, const float* __restrict__ bg2v,
    const float* __restrict__ Wk1, const float* __restrict__ bk1v,
    const float* __restrict__ Wk2, const float* __restrict__ bk2v,
    float* __restrict__ out)
{
    const int b = blockIdx.x;
    const int t = threadIdx.x;
    __shared__ float xs[N_];
    __shared__ float tf[H_], tg[H_], tk[H_], sk[H_];
    __shared__ float fo[N_], go[N_];
    __shared__ float sfv[H_], sgv[H_];
    __shared__ float red[12];

    xs[t] = x[b * N_ + t];
    __syncthreads();
    {
        float acc[12];
        const float4* rows[12];
        #pragma unroll
        for (int m = 0; m < 4; ++m) {
            const int h = t + m * 256;
            rows[m]     = (const float4*)(Wf1 + h * N_);
            rows[4 + m] = (const float4*)(Wg1 + h * N_);
            rows[8 + m] = (const float4*)(Wk1 + h * N_);
            acc[m] = bf1v[h]; acc[4 + m] = bg1v[h]; acc[8 + m] = bk1v[h];
        }
        const float4* xs4 = (const float4*)xs;
        #pragma unroll 2
        for (int c = 0; c < 64; ++c) {
            float4 a = xs4[c];
            #pragma unroll
            for (int r = 0; r < 12; ++r) {
                float4 w = rows[r][c];
                acc[r] += w.x * a.x + w.y * a.y + w.z * a.z + w.w * a.w;
            }
        }
        #pragma unroll
        for (int m = 0; m < 4; ++m) {
            const int h = t + m * 256;
            float vtf = tanhf(acc[m]);
            float vtg = tanhf(acc[4 + m]);
            float vtk = tanhf(acc[8 + m]);
            tf[h] = vtf; tg[h] = vtg; tk[h] = vtk; sk[h] = 1.0f - vtk * vtk;
        }
    }
    __syncthreads();
    float af = bf2v[t], ag = bg2v[t], ak = bk2v[t];
    {
        const float4* rf = (const float4*)(Wf2 + t * H_);
        const float4* rg = (const float4*)(Wg2 + t * H_);
        const float4* rk = (const float4*)(Wk2 + t * H_);
        #pragma unroll 2
        for (int c = 0; c < 256; ++c) {
            float4 wf = rf[c], wg = rg[c], wk = rk[c];
            float4 vf = ((const float4*)tf)[c];
            af += wf.x*vf.x + wf.y*vf.y + wf.z*vf.z + wf.w*vf.w;
            float4 vg = ((const float4*)tg)[c];
            ag += wg.x*vg.x + wg.y*vg.y + wg.z*vg.z + wg.w*vg.w;
            float4 vk = ((const float4*)tk)[c];
            ak += wk.x*vk.x + wk.y*vk.y + wk.z*vk.z + wk.w*vk.w;
        }
    }
    fo[t] = af; go[t] = ag;
    __syncthreads();
    {
        float vf[4] = {0.f,0.f,0.f,0.f}, vg[4] = {0.f,0.f,0.f,0.f};
        const float* base = Wk2 + 4 * t;
        #pragma unroll 4
        for (int i = 0; i < N_; ++i) {
            float4 w = *(const float4*)(base + i * H_);
            float fv = fo[i], gv = go[i];
            vf[0]+=w.x*fv; vf[1]+=w.y*fv; vf[2]+=w.z*fv; vf[3]+=w.w*fv;
            vg[0]+=w.x*gv; vg[1]+=w.y*gv; vg[2]+=w.z*gv; vg[3]+=w.w*gv;
        }
        #pragma unroll
        for (int c = 0; c < 4; ++c) {
            sfv[4*t+c] = sk[4*t+c]*vf[c];
            sgv[4*t+c] = sk[4*t+c]*vg[c];
        }
    }
    __syncthreads();
    float jf = 0.f, jg = 0.f;
    {
        const float* col = Wk1 + t;
        #pragma unroll 4
        for (int c = 0; c < 256; ++c) {
            float4 s4 = ((const float4*)sfv)[c];
            float4 g4 = ((const float4*)sgv)[c];
            const int h = c * 4;
            float w0 = col[(h+0)*N_], w1 = col[(h+1)*N_];
            float w2 = col[(h+2)*N_], w3 = col[(h+3)*N_];
            jf += s4.x*w0 + s4.y*w1 + s4.z*w2 + s4.w*w3;
            jg += g4.x*w0 + g4.y*w1 + g4.z*w2 + g4.w*w3;
        }
    }
    float v0 = ak*ak, v1 = jf*jf, v2 = ak*jg;
    #pragma unroll
    for (int o = 32; o > 0; o >>= 1) {
        v0 += __shfl_xor(v0, o, 64);
        v1 += __shfl_xor(v1, o, 64);
        v2 += __shfl_xor(v2, o, 64);
    }
    const int wid = t >> 6;
    if ((t & 63) == 0) {
        red[wid*3+0] = v0; red[wid*3+1] = v1; red[wid*3+2] = v2;
    }
    __syncthreads();
    const float kn2 = red[0]+red[3]+red[6]+red[9];
    const float jf2 = red[1]+red[4]+red[7]+red[10];
    const float kjg = red[2]+red[5]+red[8]+red[11];
    const float knorm = sqrtf(kn2);
    const float kn4 = kn2*kn2, kn8 = kn4*kn4;
    const float c1 = sqrtf(jf2) - 60.0f*kn8*knorm;
    const float c2 = kjg - 20.0f*kn8*kn2;
    const float scale = ((c1 > 1e-8f) || (c2 < -1e-8f)) ? 0.5f : 1.0f;
    out[b*N_+t] = (af+ag)*scale;
}

extern "C" void kernel_launch(void* const* d_in, const int* in_sizes, int n_in,
                              void* d_out, int out_size, void* d_ws, size_t ws_size,
                              hipStream_t stream) {
    const float* x    = (const float*)d_in[1];
    const float* Wf1  = (const float*)d_in[2];
    const float* bf1v = (const float*)d_in[3];
    const float* Wf2  = (const float*)d_in[4];
    const float* bf2v = (const float*)d_in[5];
    const float* Wg1  = (const float*)d_in[6];
    const float* bg1v = (const float*)d_in[7];
    const float* Wg2  = (const float*)d_in[8];
    const float* bg2v = (const float*)d_in[9];
    const float* Wk1  = (const float*)d_in[10];
    const float* bk1v = (const float*)d_in[11];
    const float* Wk2  = (const float*)d_in[12];
    const float* bk2v = (const float*)d_in[13];
    float* out = (float*)d_out;

    if (ws_size < (size_t)WS_FLOATS * sizeof(float)) {
        manifold_fused<<<BS_, 256, 0, stream>>>(
            x, Wf1, bf1v, Wf2, bf2v, Wg1, bg1v, Wg2, bg2v,
            Wk1, bk1v, Wk2, bk2v, out);
        return;
    }

    float* ws    = (float*)d_ws;
    float* sk    = ws + WS_SK;
    float* oacc  = ws + WS_OACC;
    float* opart = ws + WS_OPART;
    float* jpart = ws + WS_JPART;

    k12t      <<<768, 256, 0, stream>>>(x, Wf1, bf1v, Wg1, bg1v, Wk1, bk1v,
                                        Wf2, bf2v, Wg2, bg2v, Wk2, bk2v,
                                        sk, opart);
    k25_reduce<<<384, 256, 0, stream>>>(opart, oacc);
    k3_vj     <<<512, 256, 0, stream>>>(Wk1, Wk2, oacc, sk, jpart);
    k4_final  <<<BS_, 256, 0, stream>>>(oacc, jpart, out);
}